// Round 10
// baseline (108.559 us; speedup 1.0000x reference)
//
#include <hip/hip_runtime.h>
#include <stdint.h>

#define NN 4096
#define NB2 16         // NN / 256
#define BK 64          // K-step

// trimm grid: [0,260) units (tile (bi,bj), d=bi-bj desc; nu(d)=ceil((d+1)/4)
// K-units per tile, each <=16 K-tiles), [260,380) strict-upper zero tiles.
#define NUNITS 260
#define TGRID 380

// prep grid: [0,4096) A rows, [4096,8192) B 64x64 subtiles,
// [8192,8504) zero-init for split C tiles (78 tiles x 4 stripes)
#define PGRID 8504

typedef __bf16 bf16x8 __attribute__((ext_vector_type(8)));
typedef float f32x4 __attribute__((ext_vector_type(4)));
typedef unsigned short ushort8 __attribute__((ext_vector_type(8)));

// RTNE fp32 -> bf16
__device__ __forceinline__ unsigned short f2bf(float x) {
    union { float f; unsigned int u; } v; v.f = x;
    unsigned int u = v.u;
    u += 0x7fffu + ((u >> 16) & 1u);
    return (unsigned short)(u >> 16);
}

// async global->LDS, 16B per lane; LDS dest is wave-uniform base + lane*16
#define GLOAD16(g, l) __builtin_amdgcn_global_load_lds( \
    (const __attribute__((address_space(1))) unsigned int*)(g), \
    (__attribute__((address_space(3))) unsigned int*)(l), 16, 0, 0)

// split tile index z (0..77) -> (bi,bj), d descending 15..4 (nu>=2 tiles)
__device__ __forceinline__ void split_map(int z, int& bi, int& bj) {
    int d = 15;
    while (z >= NB2 - d) { z -= NB2 - d; --d; }
    bj = z; bi = z + d;
}

// ---- fused prep: A lower-prefix convert, B lower transpose-convert, split-C zero ----
__global__ __launch_bounds__(256) void prep(const float* __restrict__ A,
                                            const float* __restrict__ B,
                                            unsigned short* __restrict__ Ab,
                                            unsigned short* __restrict__ Bt,
                                            float* __restrict__ C) {
    __shared__ float tile[64][65];
    int bid = blockIdx.x;
    int tid = threadIdx.x;

    if (bid < 4096) {
        // A row i: convert fp32 prefix [0, ((i>>8)+1)*256) to bf16
        int i = bid;
        int nslots = ((i >> 8) + 1) * 32;   // 8 floats per slot
        const float4* src = reinterpret_cast<const float4*>(A + (size_t)i * NN);
        unsigned short* dst = Ab + (size_t)i * NN;
        for (int p = tid; p < nslots; p += 256) {
            float4 x0 = src[p * 2], x1 = src[p * 2 + 1];
            ushort8 o;
            o[0] = f2bf(x0.x); o[1] = f2bf(x0.y); o[2] = f2bf(x0.z); o[3] = f2bf(x0.w);
            o[4] = f2bf(x1.x); o[5] = f2bf(x1.y); o[6] = f2bf(x1.z); o[7] = f2bf(x1.w);
            *reinterpret_cast<ushort8*>(dst + p * 8) = o;
        }
        return;
    }
    if (bid < 8192) {
        // B 64x64 subtile transpose: needed iff k64 >= (n64 & ~3) (256-tile lower superset)
        int s = bid - 4096;
        int n64 = s >> 6, k64 = s & 63;
        if (k64 < (n64 & ~3)) return;
        int n0 = n64 * 64, k0 = k64 * 64;
        int tx = tid & 63, ty = tid >> 6;
#pragma unroll
        for (int r = 0; r < 16; ++r) {
            int k = ty + r * 4;
            tile[k][tx] = B[(size_t)(k0 + k) * NN + n0 + tx];
        }
        __syncthreads();
#pragma unroll
        for (int r = 0; r < 16; ++r) {
            int n = ty + r * 4;
            Bt[(size_t)(n0 + n) * NN + k0 + tx] = f2bf(tile[tx][n]);
        }
        return;
    }
    // zero-init split C tile (atomicAdd targets; re-zeroed every call)
    {
        int zb = bid - 8192;            // 0..311
        int bi, bj; split_map(zb >> 2, bi, bj);
        int part = zb & 3;              // 64-row stripe
        float4 zf = make_float4(0.f, 0.f, 0.f, 0.f);
        float4* cp = reinterpret_cast<float4*>(C + (size_t)(bi * 256 + part * 64) * NN + (size_t)bj * 256);
#pragma unroll
        for (int i2 = 0; i2 < 16; ++i2) {
            int slot = tid + i2 * 256;
            int row = slot >> 6, c4 = slot & 63;
            cp[(size_t)row * (NN / 4) + c4] = zf;
        }
    }
}

// ---- triangular GEMM: 256^2 tile, 8 waves, counted-vmcnt 2-deep pipeline ----
__global__ __launch_bounds__(512, 2) void trimm(const unsigned short* __restrict__ Ab,
                                                const unsigned short* __restrict__ Bt,
                                                float* __restrict__ C) {
    int bid = blockIdx.x;
    int tid = threadIdx.x;
    int lane = tid & 63;
    int w = tid >> 6;          // 0..7

    if (bid >= NUNITS) {
        // strict upper 256^2 tile: zero-fill
        int r = bid - NUNITS, bi = 0;
        while (r >= NB2 - 1 - bi) { r -= NB2 - 1 - bi; ++bi; }
        int bj = bi + 1 + r;
        float4 z = make_float4(0.f, 0.f, 0.f, 0.f);
        float4* cp = reinterpret_cast<float4*>(C + (size_t)bi * 256 * NN + (size_t)bj * 256);
#pragma unroll
        for (int i2 = 0; i2 < 32; ++i2) {
            int slot = tid + i2 * 512;
            int row = slot >> 6, c4 = slot & 63;
            cp[(size_t)row * (NN / 4) + c4] = z;
        }
        return;
    }

    // unit decode: d desc 15..0; nu(d)=ceil((d+1)/4) units per tile;
    // tile has ntk = 4*(d+1) K-tiles of BK=64.
    int bi, bj, k_lo, nt;
    bool atom;
    {
        int r = bid, d = 15, nu;
        for (;;) {
            nu = (d + 4) >> 2;
            int cnt = (NB2 - d) * nu;
            if (r < cnt) break;
            r -= cnt; --d;
        }
        int t = r / nu, part = r - t * nu;
        bj = t; bi = t + d;
        atom = (nu > 1);
        int ntk = 4 * (d + 1);
        int ntb = ntk / nu, rem = ntk % nu;
        nt = ntb + (part < rem ? 1 : 0);
        int skip = part * ntb + (part < rem ? part : rem);
        k_lo = bj * 256 + skip * BK;
    }
    int k_hi = k_lo + nt * BK;

    __shared__ unsigned short As[2][256 * 64];   // 2 x 32 KB
    __shared__ unsigned short Bs[2][256 * 64];   // 2 x 32 KB  (128 KB total)

    int wr = w >> 2;           // 0..1  (M half: 128 rows)
    int wc = w & 3;            // 0..3  (N quarter: 64 cols)

    // staging: LDS linear [row][8 x 16B-chunk]; source pre-swizzled so stored
    // chunk c of row r holds global chunk c^(r&7). Thread t covers rows
    // g*64 + (t>>3), chunk t&7, g=0..3 (per matrix).
    int srow = tid >> 3;
    int schunk = ((tid & 7) ^ (srow & 7)) * 8;
    const unsigned short* gA = Ab + (size_t)(bi * 256 + srow) * NN + schunk;
    const unsigned short* gB = Bt + (size_t)(bj * 256 + srow) * NN + schunk;

    f32x4 acc[8][4];
#pragma unroll
    for (int m = 0; m < 8; ++m)
#pragma unroll
        for (int n = 0; n < 4; ++n)
            acc[m][n] = (f32x4){0.f, 0.f, 0.f, 0.f};

    // fragment reads: row = base + fr; want global chunk (lane>>4) [kslot0] /
    // 4|(lane>>4) [kslot1]; stored at chunk^(row&7), row&7 == lane&7.
    int fr = lane & 15;
    int c0 = (((lane >> 4) ^ (lane & 7)) * 8);
    int c1 = ((((lane >> 4) | 4) ^ (lane & 7)) * 8);
    int arow = wr * 128 + fr;
    int brow = wc * 64 + fr;

#define STAGE(bufsel, kk) do { \
        unsigned short* la_ = &As[bufsel][0] + tid * 8; \
        unsigned short* lb_ = &Bs[bufsel][0] + tid * 8; \
        GLOAD16(gA + (kk), la_); \
        GLOAD16(gA + (kk) + (size_t)64 * NN, la_ + 4096); \
        GLOAD16(gA + (kk) + (size_t)128 * NN, la_ + 8192); \
        GLOAD16(gA + (kk) + (size_t)192 * NN, la_ + 12288); \
        GLOAD16(gB + (kk), lb_); \
        GLOAD16(gB + (kk) + (size_t)64 * NN, lb_ + 4096); \
        GLOAD16(gB + (kk) + (size_t)128 * NN, lb_ + 8192); \
        GLOAD16(gB + (kk) + (size_t)192 * NN, lb_ + 12288); \
    } while (0)

    // prologue: 2-deep (16 loads in flight); nt >= 4 always
    STAGE(0, k_lo);
    STAGE(1, k_lo + BK);
    int cur = 0;

    for (int t = 0; t < nt; ++t) {
        // own 8 oldest loads (buf[cur]) landed; 8 newer may stay in flight
        asm volatile("s_waitcnt vmcnt(8)" ::: "memory");
        __builtin_amdgcn_s_barrier();   // all waves' buf[cur] loads visible

        const unsigned short* Ac = &As[cur][0];
        const unsigned short* Bc = &Bs[cur][0];
        bf16x8 b0[4], b1[4];
#pragma unroll
        for (int n = 0; n < 4; ++n) {
            b0[n] = *reinterpret_cast<const bf16x8*>(&Bc[(brow + n * 16) * 64 + c0]);
            b1[n] = *reinterpret_cast<const bf16x8*>(&Bc[(brow + n * 16) * 64 + c1]);
        }
        // M-half 0 (m=0..3)
        {
            bf16x8 a0[4], a1[4];
#pragma unroll
            for (int m = 0; m < 4; ++m) {
                a0[m] = *reinterpret_cast<const bf16x8*>(&Ac[(arow + m * 16) * 64 + c0]);
                a1[m] = *reinterpret_cast<const bf16x8*>(&Ac[(arow + m * 16) * 64 + c1]);
            }
            __builtin_amdgcn_s_setprio(1);
#pragma unroll
            for (int m = 0; m < 4; ++m)
#pragma unroll
                for (int n = 0; n < 4; ++n) {
                    acc[m][n] = __builtin_amdgcn_mfma_f32_16x16x32_bf16(a0[m], b0[n], acc[m][n], 0, 0, 0);
                    acc[m][n] = __builtin_amdgcn_mfma_f32_16x16x32_bf16(a1[m], b1[n], acc[m][n], 0, 0, 0);
                }
            __builtin_amdgcn_s_setprio(0);
        }
        // M-half 1 (m=4..7)
        {
            bf16x8 a0[4], a1[4];
#pragma unroll
            for (int m = 0; m < 4; ++m) {
                a0[m] = *reinterpret_cast<const bf16x8*>(&Ac[(arow + 64 + m * 16) * 64 + c0]);
                a1[m] = *reinterpret_cast<const bf16x8*>(&Ac[(arow + 64 + m * 16) * 64 + c1]);
            }
            __builtin_amdgcn_s_setprio(1);
#pragma unroll
            for (int m = 0; m < 4; ++m)
#pragma unroll
                for (int n = 0; n < 4; ++n) {
                    acc[m + 4][n] = __builtin_amdgcn_mfma_f32_16x16x32_bf16(a0[m], b0[n], acc[m + 4][n], 0, 0, 0);
                    acc[m + 4][n] = __builtin_amdgcn_mfma_f32_16x16x32_bf16(a1[m], b1[n], acc[m + 4][n], 0, 0, 0);
                }
            __builtin_amdgcn_s_setprio(0);
        }

        __builtin_amdgcn_s_barrier();   // all waves done reading buf[cur]

        // stage tile t+2 into buf[cur]; uniform dummy re-stage at tail keeps
        // per-wave vmcnt arithmetic constant (8 issued every iteration)
        int kn = k_lo + (t + 2) * BK;
        if (kn >= k_hi) kn = k_lo;
        STAGE(cur, kn);

        cur ^= 1;
    }
    asm volatile("s_waitcnt vmcnt(0)" ::: "memory");  // drain dummies
#undef STAGE

    // epilogue: C/D layout col = lane&15, row = (lane>>4)*4 + reg
    int crow0 = bi * 256 + wr * 128 + (lane >> 4) * 4;
    int ccol0 = bj * 256 + wc * 64 + fr;
    if (atom) {
#pragma unroll
        for (int m = 0; m < 8; ++m)
#pragma unroll
            for (int n = 0; n < 4; ++n) {
                float* cp = C + (size_t)(crow0 + m * 16) * NN + ccol0 + n * 16;
#pragma unroll
                for (int r2 = 0; r2 < 4; ++r2)
                    atomicAdd(&cp[(size_t)r2 * NN], acc[m][n][r2]);
            }
    } else {
#pragma unroll
        for (int m = 0; m < 8; ++m)
#pragma unroll
            for (int n = 0; n < 4; ++n) {
                float* cp = C + (size_t)(crow0 + m * 16) * NN + ccol0 + n * 16;
#pragma unroll
                for (int r2 = 0; r2 < 4; ++r2)
                    cp[(size_t)r2 * NN] = acc[m][n][r2];
            }
    }
}

extern "C" void kernel_launch(void* const* d_in, const int* in_sizes, int n_in,
                              void* d_out, int out_size, void* d_ws, size_t ws_size,
                              hipStream_t stream) {
    const float* A = (const float*)d_in[0];
    const float* B = (const float*)d_in[1];
    float* C = (float*)d_out;
    unsigned short* Ab = (unsigned short*)d_ws;            // 32 MB bf16 A (lower tiles valid)
    unsigned short* Bt = Ab + (size_t)NN * NN;             // 32 MB bf16 B^T (needed tiles valid)
    prep<<<PGRID, 256, 0, stream>>>(A, B, Ab, Bt, C);
    trimm<<<TGRID, 512, 0, stream>>>(Ab, Bt, C);
}

// Round 11
// 81.522 us; speedup vs baseline: 1.3316x; 1.3316x over previous
//
#include <hip/hip_runtime.h>
#include <stdint.h>

#define NN 4096
#define NB 32          // NN / 128
#define BK 64          // K-step (2 x 16x16x32 MFMA k-slots)

// trimm grid: [0,709) K-units over lower tiles, d=bi-bj descending,
// nu(d)=ceil((d+1)/14) units/tile (max unit 28 K-tiles);
// [709,1205) strict-upper zero tiles.
#define NUNITS 709
#define ZBASE 709
#define TGRID 1205

// prep grid: [0,4096) A rows, [4096,8192) B 64x64 subtiles,
// [8192,8363) zero-init for split C tiles (d>=14: 171 tiles)
#define PGRID 8363

typedef __bf16 bf16x8 __attribute__((ext_vector_type(8)));
typedef float f32x4 __attribute__((ext_vector_type(4)));
typedef unsigned short ushort8 __attribute__((ext_vector_type(8)));

// RTNE fp32 -> bf16
__device__ __forceinline__ unsigned short f2bf(float x) {
    union { float f; unsigned int u; } v; v.f = x;
    unsigned int u = v.u;
    u += 0x7fffu + ((u >> 16) & 1u);
    return (unsigned short)(u >> 16);
}

// async global->LDS, 16B per lane; LDS dest is wave-uniform base + lane*16
#define GLOAD16(g, l) __builtin_amdgcn_global_load_lds( \
    (const __attribute__((address_space(1))) unsigned int*)(g), \
    (__attribute__((address_space(3))) unsigned int*)(l), 16, 0, 0)

// ---- fused prep: A lower-prefix convert, B lower transpose-convert, split-C zero ----
__global__ __launch_bounds__(256) void prep(const float* __restrict__ A,
                                            const float* __restrict__ B,
                                            unsigned short* __restrict__ Ab,
                                            unsigned short* __restrict__ Bt,
                                            float* __restrict__ C) {
    __shared__ float tile[64][65];
    int bid = blockIdx.x;
    int tid = threadIdx.x;

    if (bid < 4096) {
        // A row i: convert fp32 prefix [0, ((i>>7)+1)*128) to bf16
        int i = bid;
        int nslots = (((i >> 7) + 1) * 128) >> 3;   // 8 floats per slot
        const float4* src = reinterpret_cast<const float4*>(A + (size_t)i * NN);
        unsigned short* dst = Ab + (size_t)i * NN;
        for (int p = tid; p < nslots; p += 256) {
            float4 x0 = src[p * 2], x1 = src[p * 2 + 1];
            ushort8 o;
            o[0] = f2bf(x0.x); o[1] = f2bf(x0.y); o[2] = f2bf(x0.z); o[3] = f2bf(x0.w);
            o[4] = f2bf(x1.x); o[5] = f2bf(x1.y); o[6] = f2bf(x1.z); o[7] = f2bf(x1.w);
            *reinterpret_cast<ushort8*>(dst + p * 8) = o;
        }
        return;
    }
    if (bid < 8192) {
        // B 64x64 subtile transpose: needed iff k64 >= (n64 & ~1)  (128-tile lower superset)
        int s = bid - 4096;
        int n64 = s >> 6, k64 = s & 63;
        if (k64 < (n64 & ~1)) return;
        int n0 = n64 * 64, k0 = k64 * 64;
        int tx = tid & 63, ty = tid >> 6;
#pragma unroll
        for (int r = 0; r < 16; ++r) {
            int k = ty + r * 4;
            tile[k][tx] = B[(size_t)(k0 + k) * NN + n0 + tx];
        }
        __syncthreads();
#pragma unroll
        for (int r = 0; r < 16; ++r) {
            int n = ty + r * 4;
            Bt[(size_t)(n0 + n) * NN + k0 + tx] = f2bf(tile[tx][n]);
        }
        return;
    }
    // zero-init split C tile (atomicAdd targets; d>=14, d descending)
    {
        int z = bid - 8192;             // 0..170
        int d = NB - 1, bi, bj;
        for (;;) {
            int cnt = NB - d;
            if (z < cnt) { bj = z; bi = z + d; break; }
            z -= cnt; --d;
        }
        float4 zf = make_float4(0.f, 0.f, 0.f, 0.f);
        float4* cp = reinterpret_cast<float4*>(C + (size_t)bi * 128 * NN + (size_t)bj * 128);
#pragma unroll
        for (int i2 = 0; i2 < 16; ++i2) {
            int slot = tid + i2 * 256;
            int row = slot >> 5, c4 = slot & 31;
            cp[(size_t)row * (NN / 4) + c4] = zf;
        }
    }
}

// ---- triangular GEMM: 128^2 tile, BK=64, 2 blocks/CU, counted-vmcnt 2-deep ----
__global__ __launch_bounds__(256, 2) void trimm(const unsigned short* __restrict__ Ab,
                                                const unsigned short* __restrict__ Bt,
                                                float* __restrict__ C) {
    int bid = blockIdx.x;
    int tid = threadIdx.x;
    int lane = tid & 63;
    int w = tid >> 6;

    if (bid >= ZBASE) {
        // strict upper tile: zero-fill 128x128
        int t = bid - ZBASE;
        int r = 0, cnt = NB - 1;
        while (t >= cnt) { t -= cnt; ++r; --cnt; }
        int bi = r, bj = r + 1 + t;
        float4 z = make_float4(0.f, 0.f, 0.f, 0.f);
        float4* cp = reinterpret_cast<float4*>(C + (size_t)bi * 128 * NN + (size_t)bj * 128);
#pragma unroll
        for (int i2 = 0; i2 < 16; ++i2) {
            int slot = tid + i2 * 256;
            int row = slot >> 5, c4 = slot & 31;
            cp[(size_t)row * (NN / 4) + c4] = z;
        }
        return;
    }

    // unit decode: d desc 31..0; nu(d)=ceil((d+1)/14); tile has 2*(d+1) K-tiles
    int bi, bj, k_lo, nt;
    bool atom;
    {
        int r = bid, d = NB - 1, nu;
        for (;;) {
            nu = (d + 14) / 14;
            int cnt = (NB - d) * nu;
            if (r < cnt) break;
            r -= cnt; --d;
        }
        int t = r / nu, part = r - t * nu;
        bj = t; bi = t + d;
        atom = (nu > 1);
        int ntk = 2 * (d + 1);
        int ntb = ntk / nu, rem = ntk % nu;
        nt = ntb + (part < rem ? 1 : 0);
        int skip = part * ntb + (part < rem ? part : rem);
        k_lo = bj * 128 + skip * BK;
    }
    int k_hi = k_lo + nt * BK;

    __shared__ unsigned short As[2][128 * BK];   // 2 x 16 KB
    __shared__ unsigned short Bs[2][128 * BK];   // 2 x 16 KB  (64 KB total -> 2 blocks/CU)

    int wr = w >> 1, wc = w & 1;

    // staging: LDS linear [row][8 x 16B-chunk]; source pre-swizzled so stored
    // chunk c of row r holds global chunk c^(r&7). Thread t covers rows
    // g*32 + (t>>3), chunk t&7, g=0..3 (per matrix).
    int srow = tid >> 3;
    int schunk = ((tid & 7) ^ (srow & 7)) * 8;
    const unsigned short* gA = Ab + (size_t)(bi * 128 + srow) * NN + schunk;
    const unsigned short* gB = Bt + (size_t)(bj * 128 + srow) * NN + schunk;

    f32x4 acc[4][4];
#pragma unroll
    for (int mi = 0; mi < 4; ++mi)
#pragma unroll
        for (int ni = 0; ni < 4; ++ni)
            acc[mi][ni] = (f32x4){0.f, 0.f, 0.f, 0.f};

    // fragment reads: row = (wr|wc)*64 + m*16 + (lane&15); want global chunk
    // (lane>>4) [kslot0] / 4|(lane>>4) [kslot1]; stored at chunk^(row&7),
    // row&7 == lane&7.
    int fr = lane & 15;
    int c0 = (((lane >> 4) ^ (lane & 7)) * 8);
    int c1 = ((((lane >> 4) | 4) ^ (lane & 7)) * 8);
    int arow = wr * 64 + fr;
    int brow = wc * 64 + fr;

#define STAGE(bufsel, kk) do { \
        unsigned short* la_ = &As[bufsel][0] + tid * 8; \
        unsigned short* lb_ = &Bs[bufsel][0] + tid * 8; \
        GLOAD16(gA + (kk), la_); \
        GLOAD16(gA + (kk) + (size_t)32 * NN, la_ + 2048); \
        GLOAD16(gA + (kk) + (size_t)64 * NN, la_ + 4096); \
        GLOAD16(gA + (kk) + (size_t)96 * NN, la_ + 6144); \
        GLOAD16(gB + (kk), lb_); \
        GLOAD16(gB + (kk) + (size_t)32 * NN, lb_ + 2048); \
        GLOAD16(gB + (kk) + (size_t)64 * NN, lb_ + 4096); \
        GLOAD16(gB + (kk) + (size_t)96 * NN, lb_ + 6144); \
    } while (0)

    // prologue: 2-deep (16 loads in flight); nt >= 2 always
    STAGE(0, k_lo);
    STAGE(1, k_lo + BK);
    int cur = 0;

    for (int t = 0; t < nt; ++t) {
        // own 8 oldest loads (buf[cur]) landed; 8 newer may stay in flight
        asm volatile("s_waitcnt vmcnt(8)" ::: "memory");
        __builtin_amdgcn_s_barrier();   // all waves' buf[cur] loads visible

        const unsigned short* Ac = &As[cur][0];
        const unsigned short* Bc = &Bs[cur][0];
        bf16x8 a0[4], a1[4], b0[4], b1[4];
#pragma unroll
        for (int m = 0; m < 4; ++m) {
            a0[m] = *reinterpret_cast<const bf16x8*>(&Ac[(arow + m * 16) * BK + c0]);
            a1[m] = *reinterpret_cast<const bf16x8*>(&Ac[(arow + m * 16) * BK + c1]);
        }
#pragma unroll
        for (int n = 0; n < 4; ++n) {
            b0[n] = *reinterpret_cast<const bf16x8*>(&Bc[(brow + n * 16) * BK + c0]);
            b1[n] = *reinterpret_cast<const bf16x8*>(&Bc[(brow + n * 16) * BK + c1]);
        }
        __builtin_amdgcn_s_setprio(1);
#pragma unroll
        for (int m = 0; m < 4; ++m)
#pragma unroll
            for (int n = 0; n < 4; ++n) {
                acc[m][n] = __builtin_amdgcn_mfma_f32_16x16x32_bf16(a0[m], b0[n], acc[m][n], 0, 0, 0);
                acc[m][n] = __builtin_amdgcn_mfma_f32_16x16x32_bf16(a1[m], b1[n], acc[m][n], 0, 0, 0);
            }
        __builtin_amdgcn_s_setprio(0);

        __builtin_amdgcn_s_barrier();   // all waves done reading buf[cur]

        // stage tile t+2 into buf[cur]; uniform dummy re-stage at tail keeps
        // per-wave vmcnt arithmetic constant (8 issued every iteration)
        int kn = k_lo + (t + 2) * BK;
        if (kn >= k_hi) kn = k_lo;
        STAGE(cur, kn);

        cur ^= 1;
    }
    asm volatile("s_waitcnt vmcnt(0)" ::: "memory");  // drain dummies before LDS dealloc
#undef STAGE

    // epilogue: C/D layout col = lane&15, row = (lane>>4)*4 + reg
    int crow0 = bi * 128 + wr * 64 + (lane >> 4) * 4;
    int ccol0 = bj * 128 + wc * 64 + fr;
    if (atom) {
#pragma unroll
        for (int mi = 0; mi < 4; ++mi)
#pragma unroll
            for (int ni = 0; ni < 4; ++ni) {
                float* cp = C + (size_t)(crow0 + mi * 16) * NN + ccol0 + ni * 16;
#pragma unroll
                for (int r2 = 0; r2 < 4; ++r2)
                    atomicAdd(&cp[(size_t)r2 * NN], acc[mi][ni][r2]);
            }
    } else {
#pragma unroll
        for (int mi = 0; mi < 4; ++mi)
#pragma unroll
            for (int ni = 0; ni < 4; ++ni) {
                float* cp = C + (size_t)(crow0 + mi * 16) * NN + ccol0 + ni * 16;
#pragma unroll
                for (int r2 = 0; r2 < 4; ++r2)
                    cp[(size_t)r2 * NN] = acc[mi][ni][r2];
            }
    }
}

extern "C" void kernel_launch(void* const* d_in, const int* in_sizes, int n_in,
                              void* d_out, int out_size, void* d_ws, size_t ws_size,
                              hipStream_t stream) {
    const float* A = (const float*)d_in[0];
    const float* B = (const float*)d_in[1];
    float* C = (float*)d_out;
    unsigned short* Ab = (unsigned short*)d_ws;            // 32 MB bf16 A (lower tiles valid)
    unsigned short* Bt = Ab + (size_t)NN * NN;             // 32 MB bf16 B^T (needed tiles valid)
    prep<<<PGRID, 256, 0, stream>>>(A, B, Ab, Bt, C);
    trimm<<<TGRID, 256, 0, stream>>>(Ab, Bt, C);
}